// Round 9
// baseline (2091.626 us; speedup 1.0000x reference)
//
#include <hip/hip_runtime.h>
#include <hip/hip_fp16.h>

#define TM1   127
#define NE    128
#define NT    1024
#define NB    256            // 4 batches/block, 1 block/CU
#define ROWW  65             // uint words per E row (128 fp16 + pad)
#define SDCW  264            // floats/batch in sdc: d at 0..127, c at 132..259 (bank-split)
#define UWSW  132            // float2/batch in uws: h0 at 0..63, h1 at 66..129 (bank-split)

#if __has_builtin(__builtin_amdgcn_exp2f)
#define EXP2(x) __builtin_amdgcn_exp2f(x)
#else
#define EXP2(x) exp2f(x)
#endif
#define RCP(x) __builtin_amdgcn_rcpf(x)
#define K2 2.885390081777927f   // 2*log2(e); tanh(x) = 1 - 2*rcp(exp2(K2 x)+1)

typedef _Float16 h2 __attribute__((ext_vector_type(2)));

#if __has_builtin(__builtin_amdgcn_fdot2)
__device__ __forceinline__ float DOT2(h2 a, h2 b, float c){
    return __builtin_amdgcn_fdot2(a, b, c, false);       // v_dot2_f32_f16
}
#else
__device__ __forceinline__ float DOT2(h2 a, h2 b, float c){
    return fmaf((float)a.x, (float)b.x, fmaf((float)a.y, (float)b.y, c));
}
#endif

__device__ __forceinline__ float fast_sig(float x){ return RCP(1.0f + __expf(-x)); }
__device__ __forceinline__ float fast_tanh(float x){ float e = __expf(2.0f*x); return 1.0f - 2.0f*RCP(e+1.0f); }

// Pack W1dc rows 0..255 as f32 k-quads (float4) and Wh as f16 k-octets (uint4).
__global__ void pack_weights(const float* __restrict__ W1, const float* __restrict__ Wh,
                             float4* __restrict__ W1p, uint4* __restrict__ Whh) {
    const int t = blockIdx.x*256 + threadIdx.x;
    if (t < 8192) {                       // W1p[k4*128+e], k4=0..63 covers k=0..255 ([d;c])
        const int k4 = t >> 7, e = t & 127;
        W1p[t] = make_float4(W1[(4*k4+0)*NE + e], W1[(4*k4+1)*NE + e],
                             W1[(4*k4+2)*NE + e], W1[(4*k4+3)*NE + e]);
    } else if (t < 16384) {               // Whh[k8*512+j], k8=0..15 covers k=0..127
        const int t2 = t - 8192;
        const int k8 = t2 >> 9, j = t2 & 511;
        unsigned h[8];
        #pragma unroll
        for (int i = 0; i < 8; ++i)
            h[i] = (unsigned)__half_as_ushort(__float2half(Wh[(8*k8+i)*512 + j]));
        Whh[t2] = make_uint4(h[0] | (h[1]<<16), h[2] | (h[3]<<16),
                             h[4] | (h[5]<<16), h[6] | (h[7]<<16));
    }
}

__global__ __launch_bounds__(NT, 4)      // 4 waves/EU => 16 waves/CU => 128 VGPR cap
void decoder_kernel(const float* __restrict__ Xg,     // (1024,127,128)
                    const float* __restrict__ yprev,  // (1024,127)
                    const float* __restrict__ W1,     // (384,128)
                    const float* __restrict__ b1,
                    const float* __restrict__ W2,     // (128)
                    const float* __restrict__ b2v,
                    const float* __restrict__ Wfc,    // (129)
                    const float* __restrict__ bfcv,
                    const float* __restrict__ Wx,     // (512)
                    const float* __restrict__ blv,    // (512)
                    const float* __restrict__ Wf,     // (256)
                    const float* __restrict__ bfv,
                    const float4* __restrict__ W1p,   // f32 quads [64][128]
                    const uint4* __restrict__ Whh,    // f16 octets [16][512]
                    float* __restrict__ out)          // (1024)
{
    // LDS total: 133120+4224+4224+8192+2048+2048+2048+2048+2048+512+32+64+1024 = 161,632
    __shared__ __align__(16) unsigned Eu [4*128*ROWW]; // E handoff -> W1p f32 cache
    __shared__ __align__(16) float  sdc  [4*SDCW];     // d/c, bank-split halves
    __shared__ __align__(16) float2 uws  [4*UWSW];     // (exp2(K2 u), -2*W2[e]), bank-split
    __shared__ __align__(16) float  zsc  [2048];       // [b*512+j] d@Wh; epilogue scratch
    __shared__ __align__(16) float  XWfcs[512];
    __shared__ __align__(16) float  betas[512];
    __shared__ __align__(16) float  ys   [512];
    __shared__ __align__(16) float4 wxf4 [128];
    __shared__ __align__(16) float4 blf4 [128];
    __shared__ float w2m2[128];
    __shared__ float params[8];                        // 0:wfcy 1:bfc 2:bf 4,5:pinit[h]
    __shared__ float swv[16];
    __shared__ __align__(16) __half sdch[512];         // [b*128+k]: d as f16 (for dot2)

    const int tid  = (int)threadIdx.x;
    const int lane = tid & 63;
    const int wave = tid >> 6;
    const int b0   = (int)blockIdx.x * 4;

    const float4* sdc4  = (const float4*)sdc;          // 66 quads/batch: d 0..31, c 33..64
    const uint4*  sdch4 = (const uint4*)sdch;          // [b*16 + k8]: 8 d-halfs, bcast
    __half* Eh = (__half*)Eu;

    // roles: u-waves = 0-3 (batches 0,1) and 12-15 (batches 2,3); z-waves = 4-11
    const bool is_u = (wave < 4) || (wave >= 12);
    const int  w4   = (wave < 4) ? wave : (wave - 12);
    const int  bsel = (wave < 4) ? 0 : 2;

    // phase-B mapping (t-invariant): lane -> (batch bB, row tpB, half hB)
    const int bB  = tid >> 8;
    const int tqB = (tid >> 6) & 3;
    const int tpB = tqB*32 + (lane >> 1);
    const int hB  = lane & 1;

    // ---- init ----
    if (tid < 128) {
        w2m2[tid] = -2.0f * W2[tid];
        wxf4[tid] = make_float4(Wx[tid],  Wx[128+tid],  Wx[256+tid],  Wx[384+tid]);
        blf4[tid] = make_float4(blv[tid], blv[128+tid], blv[256+tid], blv[384+tid]);
    }
    if (tid == 0) { params[0] = Wfc[NE]; params[1] = bfcv[0]; params[2] = bfv[0]; }
    if (tid == 4 || tid == 5) {                      // pinit[h] = b2/2 + sum W2[h-half]
        const int h = tid - 4;
        float s = b2v[0] * 0.5f;
        for (int i = 0; i < 64; ++i) s += W2[h*64 + i];
        params[4 + h] = s;
    }
    {   const int b = tid >> 8, r = tid & 255;       // d0 = c0 = X[b,0,0], bank-split
        sdc[b*SDCW + r + ((r >> 7) << 2)] = Xg[(size_t)(b0+b)*TM1*NE];
    }
    if (tid < 512) {                                 // f16 mirror of d0
        const int b = tid >> 7;
        sdch[tid] = __float2half(Xg[(size_t)(b0+b)*TM1*NE]);
    }
    if (tid < 512) {
        const int b = tid >> 7, g = tid & 127;
        ys[tid] = (g < TM1) ? yprev[(size_t)(b0+b)*TM1 + g] : 0.0f;
        float xw = 0.0f;                             // XWfc[t'] = X[t'].Wfc[:128]
        if (g < TM1) {
            const float4* xr = (const float4*)(Xg + ((size_t)(b0+b)*TM1 + g)*NE);
            #pragma unroll 4
            for (int i = 0; i < 32; ++i) {
                const float4 x = xr[i];
                const float4 w = *(const float4*)&Wfc[i*4];
                xw = fmaf(x.x,w.x, fmaf(x.y,w.y, fmaf(x.z,w.z, fmaf(x.w,w.w, xw))));
            }
        }
        XWfcs[tid] = xw;                             // row 127 -> 0
    }
    if (tid < 260) {                                 // E row 127 = 0 (read into regs below)
        const int b = tid / 65, m = tid - b*65;
        Eu[(b*128 + 127)*ROWW + m] = 0u;
    }

    // ---- preamble: E = exp2(K2*(b1 + X@W1x)) as fp16 ----
    {
        const int eA = tid >> 3, oA = tid & 7;
        float w1x[16];
        #pragma unroll
        for (int m = 0; m < 16; ++m) w1x[m] = W1[(256 + oA*16 + m)*NE + eA];
        const float b1r = b1[eA];
        for (int b = 0; b < 4; ++b) {
            const float* Xbase = Xg + (size_t)(b0+b)*TM1*NE;
            for (int tp = 0; tp < TM1; ++tp) {
                const float4* xr = (const float4*)(Xbase + tp*NE + oA*16);
                float s0 = 0.f, s1 = 0.f;
                #pragma unroll
                for (int q = 0; q < 4; ++q) {
                    const float4 x = xr[q];
                    float& s = (q & 1) ? s1 : s0;
                    s = fmaf(w1x[q*4+0],x.x, fmaf(w1x[q*4+1],x.y,
                        fmaf(w1x[q*4+2],x.z, fmaf(w1x[q*4+3],x.w, s))));
                }
                float s = s0 + s1;
                s += __shfl_xor(s,1); s += __shfl_xor(s,2); s += __shfl_xor(s,4);
                if (oA == 0)
                    Eh[(b*128+tp)*2*ROWW + eA] = __float2half(EXP2(K2*(s + b1r)));
            }
        }
    }
    __syncthreads();

    // ---- E -> registers (t-invariant per lane) ----
    unsigned ereg[32];
    {
        const unsigned* Erow = Eu + (bB*128 + tpB)*ROWW + hB*32;
        #pragma unroll
        for (int i = 0; i < 32; ++i) ereg[i] = Erow[i];
    }
    __syncthreads();                                 // all reads of Eu done

    // ---- overlay W1p into dead Eu LDS; Whh -> z-wave VGPRs (128-cap, no spill) ----
    {
        const uint4* src = (const uint4*)W1p;        // 131072 B <= 133120 B (Eu)
        uint4* dst = (uint4*)Eu;
        #pragma unroll
        for (int i = 0; i < 8; ++i)
            dst[tid + i*1024] = src[tid + i*1024];
    }
    uint4 whr16[16];                                 // z-waves: 16 f16-octets = 64 VGPRs
    if (!is_u) {
        const int j = (wave - 4)*64 + lane;
        #pragma unroll
        for (int k8 = 0; k8 < 16; ++k8) whr16[k8] = Whh[k8*512 + j];
    }
    __syncthreads();
    const float4* W1l = (const float4*)Eu;           // f32 quads [64][128] in LDS

    for (int t = 0; t < TM1; ++t) {
        // ==== phase A: 8 u-waves (LDS-fed, 2 batches each); 8 z-waves (reg-fed) ====
        if (is_u) {
            const int el = lane >> 1, kh = lane & 1;   // kh: d-half vs c-half of k
            const int e  = w4*32 + el;
            float a0=0.f, a1=0.f;
            #pragma unroll 4
            for (int k4 = 0; k4 < 32; ++k4) {
                const float4 wv = W1l[(kh*32 + k4)*128 + e];       // conflict-free b128
                const float4 dA = sdc4[(bsel  )*66 + kh*33 + k4];  // bcast, bank-split
                const float4 dB = sdc4[(bsel+1)*66 + kh*33 + k4];
                a0 = fmaf(wv.x,dA.x,fmaf(wv.y,dA.y,fmaf(wv.z,dA.z,fmaf(wv.w,dA.w,a0))));
                a1 = fmaf(wv.x,dB.x,fmaf(wv.y,dB.y,fmaf(wv.z,dB.z,fmaf(wv.w,dB.w,a1))));
            }
            a0 += __shfl_xor(a0,1); a1 += __shfl_xor(a1,1);        // kh merge
            if (kh == 0) {
                const float w2 = w2m2[e];
                const int ei = e + ((e >> 6) << 1);                // bank-split index
                uws[ bsel   *UWSW + ei] = make_float2(EXP2(K2*a0), w2);
                uws[(bsel+1)*UWSW + ei] = make_float2(EXP2(K2*a1), w2);
            }
        } else {
            const int j = (wave - 4)*64 + lane;
            float a0=0.f, a1=0.f, a2=0.f, a3=0.f;
            #pragma unroll
            for (int k8 = 0; k8 < 16; ++k8) {
                const uint4 wq  = whr16[k8];                 // registers, no loads
                const uint4 dq0 = sdch4[      k8];           // 8 f16 d's, uniform bcast
                const uint4 dq1 = sdch4[16 +  k8];
                const uint4 dq2 = sdch4[32 +  k8];
                const uint4 dq3 = sdch4[48 +  k8];
                const h2* wh = (const h2*)&wq;
                const h2* e0 = (const h2*)&dq0;  const h2* e1 = (const h2*)&dq1;
                const h2* e2 = (const h2*)&dq2;  const h2* e3 = (const h2*)&dq3;
                #pragma unroll
                for (int p = 0; p < 4; ++p) {
                    a0 = DOT2(wh[p], e0[p], a0);
                    a1 = DOT2(wh[p], e1[p], a1);
                    a2 = DOT2(wh[p], e2[p], a2);
                    a3 = DOT2(wh[p], e3[p], a3);
                }
            }
            zsc[       j] = a0; zsc[ 512 + j] = a1;
            zsc[1024 + j] = a2; zsc[1536 + j] = a3;
        }
        __syncthreads();                               // S1

        // ==== phase B: beta terms from E-regs: v=fma(E,EU,1); p=fma(w2,rcp(v),p) ====
        {
            const float4* uw4 = (const float4*)(uws + bB*UWSW + hB*66);
            float p0 = params[4 + hB], p1 = 0.f;
            #pragma unroll
            for (int i = 0; i < 32; ++i) {
                const unsigned ew = ereg[i];                 // registers, no LDS
                const float4 uw = uw4[i];                    // (EU0,w20,EU1,w21), 2 bcast
                const __half2 e2 = *(const __half2*)&ew;
                const float v0 = fmaf(__low2float (e2), uw.x, 1.0f);
                const float v1 = fmaf(__high2float(e2), uw.z, 1.0f);
                p0 = fmaf(uw.y, RCP(v0), p0);
                p1 = fmaf(uw.w, RCP(v1), p1);
            }
            float pb = p0 + p1;
            pb += __shfl_xor(pb, 1);                         // h-merge: full row sum
            if (t == TM1-1 && hB == 0 && tpB < TM1) betas[bB*128 + tpB] = pb;
            float prod = pb * XWfcs[bB*128 + tpB];           // row 127 -> *0
            prod += __shfl_xor(prod, 2);  prod += __shfl_xor(prod, 4);
            prod += __shfl_xor(prod, 8);  prod += __shfl_xor(prod, 16);
            prod += __shfl_xor(prod, 32);
            if (lane == 0) swv[wave] = prod;
        }
        __syncthreads();                               // S2

        // ==== gates (512 threads) ====
        if (tid < 512) {
            const int b = tid >> 7, g = tid & 127;
            const float ssum = (swv[b*4] + swv[b*4+1]) + (swv[b*4+2] + swv[b*4+3]);
            const float ytl  = fmaf(ys[b*128 + t], params[0], ssum + params[1]);
            const float4 wx = wxf4[g], bl = blf4[g];
            const float zi = fmaf(ytl, wx.x, bl.x) + zsc[b*512 +       g];
            const float zf = fmaf(ytl, wx.y, bl.y) + zsc[b*512 + 128 + g];
            const float zg = fmaf(ytl, wx.z, bl.z) + zsc[b*512 + 256 + g];
            const float zo = fmaf(ytl, wx.w, bl.w) + zsc[b*512 + 384 + g];
            const float c_old = sdc[b*SDCW + 132 + g];
            const float cn = fast_sig(zf)*c_old + fast_sig(zi)*fast_tanh(zg);
            const float dn = fast_sig(zo)*fast_tanh(cn);
            sdc[b*SDCW + g] = dn; sdc[b*SDCW + 132 + g] = cn;
            sdch[b*128 + g] = __float2half(dn);            // f16 mirror for z dot2
        }
        __syncthreads();                               // S3
    }

    // ---- epilogue: final ctx from betas + global X, then out ----
    if (tid < 512) {
        const int b = tid >> 7, e = tid & 127;
        const float* Xb = Xg + (size_t)(b0+b)*TM1*NE + e;
        float cacc = 0.0f;
        #pragma unroll 4
        for (int tp = 0; tp < TM1; ++tp)
            cacc = fmaf(betas[b*128 + tp], Xb[(size_t)tp*NE], cacc);
        zsc[tid] = fmaf(sdc[b*SDCW + e], Wf[e], cacc * Wf[128 + e]);
    }
    __syncthreads();
    if (tid < 4) {
        float s = 0.0f;
        for (int i = 0; i < 128; ++i) s += zsc[tid*128 + i];
        out[b0 + tid] = s + params[2];
    }
}

extern "C" void kernel_launch(void* const* d_in, const int* in_sizes, int n_in,
                              void* d_out, int out_size, void* d_ws, size_t ws_size,
                              hipStream_t stream) {
    (void)in_sizes; (void)n_in; (void)ws_size; (void)out_size;
    const float* Xg    = (const float*)d_in[0];
    const float* yprev = (const float*)d_in[1];
    const float* W1    = (const float*)d_in[2];
    const float* b1    = (const float*)d_in[3];
    const float* W2    = (const float*)d_in[4];
    const float* b2    = (const float*)d_in[5];
    const float* Wfc   = (const float*)d_in[6];
    const float* bfc   = (const float*)d_in[7];
    const float* Wx    = (const float*)d_in[8];
    const float* Wh    = (const float*)d_in[9];
    const float* bl    = (const float*)d_in[10];
    const float* Wf    = (const float*)d_in[11];
    const float* bf    = (const float*)d_in[12];

    float4* W1p = (float4*)d_ws;                       // 128 KB
    uint4*  Whh = (uint4*)((char*)d_ws + 131072);      // 128 KB

    pack_weights<<<96, 256, 0, stream>>>(W1, Wh, W1p, Whh);
    decoder_kernel<<<NB, NT, 0, stream>>>(
        Xg, yprev, W1, b1, W2, b2, Wfc, bfc, Wx, bl, Wf, bf, W1p, Whh, (float*)d_out);
}

// Round 10
// 1497.906 us; speedup vs baseline: 1.3964x; 1.3964x over previous
//
#include <hip/hip_runtime.h>
#include <hip/hip_fp16.h>

#define TM1   127
#define NE    128
#define NT    1024
#define NB    256            // 4 batches/block, 1 block/CU
#define ROWW  65             // uint words per E row (128 fp16 + pad)
#define SDCW  264            // floats/batch in sdc: d at 0..127, c at 132..259 (bank-split)
#define UWSW  132            // float2/batch in uws: h0 at 0..63, h1 at 66..129 (bank-split)

#if __has_builtin(__builtin_amdgcn_exp2f)
#define EXP2(x) __builtin_amdgcn_exp2f(x)
#else
#define EXP2(x) exp2f(x)
#endif
#define RCP(x) __builtin_amdgcn_rcpf(x)
#define K2 2.885390081777927f   // 2*log2(e); tanh(x) = 1 - 2*rcp(exp2(K2 x)+1)

typedef _Float16 h2 __attribute__((ext_vector_type(2)));

#if __has_builtin(__builtin_amdgcn_fdot2)
__device__ __forceinline__ float DOT2(h2 a, h2 b, float c){
    return __builtin_amdgcn_fdot2(a, b, c, false);       // v_dot2_f32_f16
}
#else
__device__ __forceinline__ float DOT2(h2 a, h2 b, float c){
    return fmaf((float)a.x, (float)b.x, fmaf((float)a.y, (float)b.y, c));
}
#endif

__device__ __forceinline__ float fast_sig(float x){ return RCP(1.0f + __expf(-x)); }
__device__ __forceinline__ float fast_tanh(float x){ float e = __expf(2.0f*x); return 1.0f - 2.0f*RCP(e+1.0f); }

// Pack W1dc rows 0..255 as f32 k-quads (float4) and Wh as f16 k-octets (uint4).
__global__ void pack_weights(const float* __restrict__ W1, const float* __restrict__ Wh,
                             float4* __restrict__ W1p, uint4* __restrict__ Whh) {
    const int t = blockIdx.x*256 + threadIdx.x;
    if (t < 8192) {                       // W1p[k4*128+e], k4=0..63 covers k=0..255 ([d;c])
        const int k4 = t >> 7, e = t & 127;
        W1p[t] = make_float4(W1[(4*k4+0)*NE + e], W1[(4*k4+1)*NE + e],
                             W1[(4*k4+2)*NE + e], W1[(4*k4+3)*NE + e]);
    } else if (t < 16384) {               // Whh[k8*512+j], k8=0..15 covers k=0..127
        const int t2 = t - 8192;
        const int k8 = t2 >> 9, j = t2 & 511;
        unsigned h[8];
        #pragma unroll
        for (int i = 0; i < 8; ++i)
            h[i] = (unsigned)__half_as_ushort(__float2half(Wh[(8*k8+i)*512 + j]));
        Whh[t2] = make_uint4(h[0] | (h[1]<<16), h[2] | (h[3]<<16),
                             h[4] | (h[5]<<16), h[6] | (h[7]<<16));
    }
}

__global__ __launch_bounds__(NT)
void decoder_kernel(const float* __restrict__ Xg,     // (1024,127,128)
                    const float* __restrict__ yprev,  // (1024,127)
                    const float* __restrict__ W1,     // (384,128)
                    const float* __restrict__ b1,
                    const float* __restrict__ W2,     // (128)
                    const float* __restrict__ b2v,
                    const float* __restrict__ Wfc,    // (129)
                    const float* __restrict__ bfcv,
                    const float* __restrict__ Wx,     // (512)
                    const float* __restrict__ blv,    // (512)
                    const float* __restrict__ Wf,     // (256)
                    const float* __restrict__ bfv,
                    const float4* __restrict__ W1p,   // f32 quads [64][128]
                    const uint4* __restrict__ Whh,    // f16 octets [16][512]
                    float* __restrict__ out)          // (1024)
{
    // LDS total: 133120+4224+4224+8192+2048+2048+2048+2048+2048+512+32+64+1024 = 161,632
    __shared__ __align__(16) unsigned Eu [4*128*ROWW]; // E handoff -> Whh f16 cache
    __shared__ __align__(16) float  sdc  [4*SDCW];     // d/c, bank-split halves
    __shared__ __align__(16) float2 uws  [4*UWSW];     // (exp2(K2 u), -2*W2[e]), bank-split
    __shared__ __align__(16) float  zsc  [2048];       // [b*512+j] d@Wh; epilogue scratch
    __shared__ __align__(16) float  XWfcs[512];
    __shared__ __align__(16) float  betas[512];
    __shared__ __align__(16) float  ys   [512];
    __shared__ __align__(16) float4 wxf4 [128];
    __shared__ __align__(16) float4 blf4 [128];
    __shared__ float w2m2[128];
    __shared__ float params[8];                        // 0:wfcy 1:bfc 2:bf 4,5:pinit[h]
    __shared__ float swv[16];
    __shared__ __align__(16) __half sdch[512];         // [b*128+k]: d as f16 (for dot2)

    const int tid  = (int)threadIdx.x;
    const int lane = tid & 63;
    const int wave = tid >> 6;
    const int b0   = (int)blockIdx.x * 4;

    const float4* sdc4  = (const float4*)sdc;          // 66 quads/batch: d 0..31, c 33..64
    const uint4*  sdch4 = (const uint4*)sdch;          // [b*16 + k8]: 8 d-halfs, bcast
    __half* Eh = (__half*)Eu;

    // roles: u-waves = 0-3 (batches 0,1) and 12-15 (batches 2,3); z-waves = 4-11
    const bool is_u = (wave < 4) || (wave >= 12);
    const int  w4   = (wave < 4) ? wave : (wave - 12);
    const int  bsel = (wave < 4) ? 0 : 2;

    // phase-B mapping (t-invariant): lane -> (batch bB, row tpB, half hB)
    const int bB  = tid >> 8;
    const int tqB = (tid >> 6) & 3;
    const int tpB = tqB*32 + (lane >> 1);
    const int hB  = lane & 1;

    // ---- init ----
    if (tid < 128) {
        w2m2[tid] = -2.0f * W2[tid];
        wxf4[tid] = make_float4(Wx[tid],  Wx[128+tid],  Wx[256+tid],  Wx[384+tid]);
        blf4[tid] = make_float4(blv[tid], blv[128+tid], blv[256+tid], blv[384+tid]);
    }
    if (tid == 0) { params[0] = Wfc[NE]; params[1] = bfcv[0]; params[2] = bfv[0]; }
    if (tid == 4 || tid == 5) {                      // pinit[h] = b2/2 + sum W2[h-half]
        const int h = tid - 4;
        float s = b2v[0] * 0.5f;
        for (int i = 0; i < 64; ++i) s += W2[h*64 + i];
        params[4 + h] = s;
    }
    {   const int b = tid >> 8, r = tid & 255;       // d0 = c0 = X[b,0,0], bank-split
        sdc[b*SDCW + r + ((r >> 7) << 2)] = Xg[(size_t)(b0+b)*TM1*NE];
    }
    if (tid < 512) {                                 // f16 mirror of d0
        const int b = tid >> 7;
        sdch[tid] = __float2half(Xg[(size_t)(b0+b)*TM1*NE]);
    }
    if (tid < 512) {
        const int b = tid >> 7, g = tid & 127;
        ys[tid] = (g < TM1) ? yprev[(size_t)(b0+b)*TM1 + g] : 0.0f;
        float xw = 0.0f;                             // XWfc[t'] = X[t'].Wfc[:128]
        if (g < TM1) {
            const float4* xr = (const float4*)(Xg + ((size_t)(b0+b)*TM1 + g)*NE);
            #pragma unroll 4
            for (int i = 0; i < 32; ++i) {
                const float4 x = xr[i];
                const float4 w = *(const float4*)&Wfc[i*4];
                xw = fmaf(x.x,w.x, fmaf(x.y,w.y, fmaf(x.z,w.z, fmaf(x.w,w.w, xw))));
            }
        }
        XWfcs[tid] = xw;                             // row 127 -> 0
    }
    if (tid < 260) {                                 // E row 127 = 0 (read into regs below)
        const int b = tid / 65, m = tid - b*65;
        Eu[(b*128 + 127)*ROWW + m] = 0u;
    }

    // ---- preamble: E = exp2(K2*(b1 + X@W1x)) as fp16 ----
    {
        const int eA = tid >> 3, oA = tid & 7;
        float w1x[16];
        #pragma unroll
        for (int m = 0; m < 16; ++m) w1x[m] = W1[(256 + oA*16 + m)*NE + eA];
        const float b1r = b1[eA];
        for (int b = 0; b < 4; ++b) {
            const float* Xbase = Xg + (size_t)(b0+b)*TM1*NE;
            for (int tp = 0; tp < TM1; ++tp) {
                const float4* xr = (const float4*)(Xbase + tp*NE + oA*16);
                float s0 = 0.f, s1 = 0.f;
                #pragma unroll
                for (int q = 0; q < 4; ++q) {
                    const float4 x = xr[q];
                    float& s = (q & 1) ? s1 : s0;
                    s = fmaf(w1x[q*4+0],x.x, fmaf(w1x[q*4+1],x.y,
                        fmaf(w1x[q*4+2],x.z, fmaf(w1x[q*4+3],x.w, s))));
                }
                float s = s0 + s1;
                s += __shfl_xor(s,1); s += __shfl_xor(s,2); s += __shfl_xor(s,4);
                if (oA == 0)
                    Eh[(b*128+tp)*2*ROWW + eA] = __float2half(EXP2(K2*(s + b1r)));
            }
        }
    }
    __syncthreads();

    // ---- E -> registers (t-invariant per lane) ----
    unsigned ereg[32];
    {
        const unsigned* Erow = Eu + (bB*128 + tpB)*ROWW + hB*32;
        #pragma unroll
        for (int i = 0; i < 32; ++i) ereg[i] = Erow[i];
    }
    __syncthreads();                                 // all reads of Eu done

    // ---- overlay Whh into dead Eu LDS (z LDS-fed; u streams W1p from L2) ----
    {
        const uint4* src = (const uint4*)Whh;        // 131072 B <= 133120 B (Eu)
        uint4* dst = (uint4*)Eu;
        #pragma unroll
        for (int i = 0; i < 8; ++i)
            dst[tid + i*1024] = src[tid + i*1024];
    }
    __syncthreads();
    const uint4* Whl4 = (const uint4*)Eu;            // f16 octets [16][512] in LDS

    for (int t = 0; t < TM1; ++t) {
        // ==== phase A: 8 u-waves (2 batches each, W1p L2 stream); 8 z-waves (LDS dot2) ====
        if (is_u) {
            const int el = lane >> 1, kh = lane & 1;   // kh: d-half vs c-half of k
            const int e  = w4*32 + el;
            float a0=0.f, a1=0.f;
            #pragma unroll 4
            for (int k4 = 0; k4 < 32; ++k4) {
                const float4 wv = W1p[(kh*32 + k4)*128 + e];       // L2 stream, shared addrs
                const float4 dA = sdc4[(bsel  )*66 + kh*33 + k4];  // bcast, bank-split
                const float4 dB = sdc4[(bsel+1)*66 + kh*33 + k4];
                a0 = fmaf(wv.x,dA.x,fmaf(wv.y,dA.y,fmaf(wv.z,dA.z,fmaf(wv.w,dA.w,a0))));
                a1 = fmaf(wv.x,dB.x,fmaf(wv.y,dB.y,fmaf(wv.z,dB.z,fmaf(wv.w,dB.w,a1))));
            }
            a0 += __shfl_xor(a0,1); a1 += __shfl_xor(a1,1);        // kh merge
            if (kh == 0) {
                const float w2 = w2m2[e];
                const int ei = e + ((e >> 6) << 1);                // bank-split index
                uws[ bsel   *UWSW + ei] = make_float2(EXP2(K2*a0), w2);
                uws[(bsel+1)*UWSW + ei] = make_float2(EXP2(K2*a1), w2);
            }
        } else {
            const int j = (wave - 4)*64 + lane;
            float a0=0.f, a1=0.f, a2=0.f, a3=0.f;
            #pragma unroll 4
            for (int k8 = 0; k8 < 16; ++k8) {
                const uint4 wq  = Whl4[k8*512 + j];          // b128, conflict-free
                const uint4 dq0 = sdch4[      k8];           // 8 f16 d's, uniform bcast
                const uint4 dq1 = sdch4[16 +  k8];
                const uint4 dq2 = sdch4[32 +  k8];
                const uint4 dq3 = sdch4[48 +  k8];
                const h2* wh = (const h2*)&wq;
                const h2* e0 = (const h2*)&dq0;  const h2* e1 = (const h2*)&dq1;
                const h2* e2 = (const h2*)&dq2;  const h2* e3 = (const h2*)&dq3;
                #pragma unroll
                for (int p = 0; p < 4; ++p) {
                    a0 = DOT2(wh[p], e0[p], a0);
                    a1 = DOT2(wh[p], e1[p], a1);
                    a2 = DOT2(wh[p], e2[p], a2);
                    a3 = DOT2(wh[p], e3[p], a3);
                }
            }
            zsc[       j] = a0; zsc[ 512 + j] = a1;
            zsc[1024 + j] = a2; zsc[1536 + j] = a3;
        }
        __syncthreads();                               // S1

        // ==== phase B: beta terms from E-regs: v=fma(E,EU,1); p=fma(w2,rcp(v),p) ====
        {
            const float4* uw4 = (const float4*)(uws + bB*UWSW + hB*66);
            float p0 = params[4 + hB], p1 = 0.f;
            #pragma unroll
            for (int i = 0; i < 32; ++i) {
                const unsigned ew = ereg[i];                 // registers, no LDS
                const float4 uw = uw4[i];                    // (EU0,w20,EU1,w21), 2 bcast
                const __half2 e2 = *(const __half2*)&ew;
                const float v0 = fmaf(__low2float (e2), uw.x, 1.0f);
                const float v1 = fmaf(__high2float(e2), uw.z, 1.0f);
                p0 = fmaf(uw.y, RCP(v0), p0);
                p1 = fmaf(uw.w, RCP(v1), p1);
            }
            float pb = p0 + p1;
            pb += __shfl_xor(pb, 1);                         // h-merge: full row sum
            if (t == TM1-1 && hB == 0 && tpB < TM1) betas[bB*128 + tpB] = pb;
            float prod = pb * XWfcs[bB*128 + tpB];           // row 127 -> *0
            prod += __shfl_xor(prod, 2);  prod += __shfl_xor(prod, 4);
            prod += __shfl_xor(prod, 8);  prod += __shfl_xor(prod, 16);
            prod += __shfl_xor(prod, 32);
            if (lane == 0) swv[wave] = prod;
        }
        __syncthreads();                               // S2

        // ==== gates (512 threads) ====
        if (tid < 512) {
            const int b = tid >> 7, g = tid & 127;
            const float ssum = (swv[b*4] + swv[b*4+1]) + (swv[b*4+2] + swv[b*4+3]);
            const float ytl  = fmaf(ys[b*128 + t], params[0], ssum + params[1]);
            const float4 wx = wxf4[g], bl = blf4[g];
            const float zi = fmaf(ytl, wx.x, bl.x) + zsc[b*512 +       g];
            const float zf = fmaf(ytl, wx.y, bl.y) + zsc[b*512 + 128 + g];
            const float zg = fmaf(ytl, wx.z, bl.z) + zsc[b*512 + 256 + g];
            const float zo = fmaf(ytl, wx.w, bl.w) + zsc[b*512 + 384 + g];
            const float c_old = sdc[b*SDCW + 132 + g];
            const float cn = fast_sig(zf)*c_old + fast_sig(zi)*fast_tanh(zg);
            const float dn = fast_sig(zo)*fast_tanh(cn);
            sdc[b*SDCW + g] = dn; sdc[b*SDCW + 132 + g] = cn;
            sdch[b*128 + g] = __float2half(dn);            // f16 mirror for z dot2
        }
        __syncthreads();                               // S3
    }

    // ---- epilogue: final ctx from betas + global X, then out ----
    if (tid < 512) {
        const int b = tid >> 7, e = tid & 127;
        const float* Xb = Xg + (size_t)(b0+b)*TM1*NE + e;
        float cacc = 0.0f;
        #pragma unroll 4
        for (int tp = 0; tp < TM1; ++tp)
            cacc = fmaf(betas[b*128 + tp], Xb[(size_t)tp*NE], cacc);
        zsc[tid] = fmaf(sdc[b*SDCW + e], Wf[e], cacc * Wf[128 + e]);
    }
    __syncthreads();
    if (tid < 4) {
        float s = 0.0f;
        for (int i = 0; i < 128; ++i) s += zsc[tid*128 + i];
        out[b0 + tid] = s + params[2];
    }
}

extern "C" void kernel_launch(void* const* d_in, const int* in_sizes, int n_in,
                              void* d_out, int out_size, void* d_ws, size_t ws_size,
                              hipStream_t stream) {
    (void)in_sizes; (void)n_in; (void)ws_size; (void)out_size;
    const float* Xg    = (const float*)d_in[0];
    const float* yprev = (const float*)d_in[1];
    const float* W1    = (const float*)d_in[2];
    const float* b1    = (const float*)d_in[3];
    const float* W2    = (const float*)d_in[4];
    const float* b2    = (const float*)d_in[5];
    const float* Wfc   = (const float*)d_in[6];
    const float* bfc   = (const float*)d_in[7];
    const float* Wx    = (const float*)d_in[8];
    const float* Wh    = (const float*)d_in[9];
    const float* bl    = (const float*)d_in[10];
    const float* Wf    = (const float*)d_in[11];
    const float* bf    = (const float*)d_in[12];

    float4* W1p = (float4*)d_ws;                       // 128 KB
    uint4*  Whh = (uint4*)((char*)d_ws + 131072);      // 128 KB

    pack_weights<<<96, 256, 0, stream>>>(W1, Wh, W1p, Whh);
    decoder_kernel<<<NB, NT, 0, stream>>>(
        Xg, yprev, W1, b1, W2, b2, Wfc, bfc, Wx, bl, Wf, bf, W1p, Whh, (float*)d_out);
}

// Round 11
// 1205.678 us; speedup vs baseline: 1.7348x; 1.2424x over previous
//
#include <hip/hip_runtime.h>
#include <hip/hip_fp16.h>

#define TM1   127
#define NE    128
#define NT    1024
#define NB    256            // 4 batches/block, 1 block/CU
#define ROWW  65             // uint words per E row (128 fp16 + pad)
#define SDCW  264            // floats/batch in sdc: d at 0..127, c at 132..259 (bank-split)
#define UWSW  132            // float2/batch in uws: h0 at 0..63, h1 at 66..129 (bank-split)

#if __has_builtin(__builtin_amdgcn_exp2f)
#define EXP2(x) __builtin_amdgcn_exp2f(x)
#else
#define EXP2(x) exp2f(x)
#endif
#define RCP(x) __builtin_amdgcn_rcpf(x)
#define K2 2.885390081777927f   // 2*log2(e); tanh(x) = 1 - 2*rcp(exp2(K2 x)+1)

typedef _Float16 h2 __attribute__((ext_vector_type(2)));

#if __has_builtin(__builtin_amdgcn_fdot2)
__device__ __forceinline__ float DOT2(h2 a, h2 b, float c){
    return __builtin_amdgcn_fdot2(a, b, c, false);       // v_dot2_f32_f16
}
#else
__device__ __forceinline__ float DOT2(h2 a, h2 b, float c){
    return fmaf((float)a.x, (float)b.x, fmaf((float)a.y, (float)b.y, c));
}
#endif

__device__ __forceinline__ float fast_sig(float x){ return RCP(1.0f + __expf(-x)); }
__device__ __forceinline__ float fast_tanh(float x){ float e = __expf(2.0f*x); return 1.0f - 2.0f*RCP(e+1.0f); }

// Pack W1dc rows 0..255 as f16 k-octets (uint4) and Wh as f16 k-octets (uint4).
__global__ void pack_weights(const float* __restrict__ W1, const float* __restrict__ Wh,
                             uint4* __restrict__ W1h, uint4* __restrict__ Whh) {
    const int t = blockIdx.x*256 + threadIdx.x;
    if (t < 4096) {                       // W1h[kq*128+e], kq=0..31 covers k=0..255 ([d;c])
        const int kq = t >> 7, e = t & 127;
        unsigned h[8];
        #pragma unroll
        for (int i = 0; i < 8; ++i)
            h[i] = (unsigned)__half_as_ushort(__float2half(W1[(kq*8+i)*NE + e]));
        W1h[t] = make_uint4(h[0] | (h[1]<<16), h[2] | (h[3]<<16),
                            h[4] | (h[5]<<16), h[6] | (h[7]<<16));
    } else if (t < 12288) {               // Whh[k8*512+j], k8=0..15 covers k=0..127
        const int t2 = t - 4096;
        const int k8 = t2 >> 9, j = t2 & 511;
        unsigned h[8];
        #pragma unroll
        for (int i = 0; i < 8; ++i)
            h[i] = (unsigned)__half_as_ushort(__float2half(Wh[(8*k8+i)*512 + j]));
        Whh[t2] = make_uint4(h[0] | (h[1]<<16), h[2] | (h[3]<<16),
                             h[4] | (h[5]<<16), h[6] | (h[7]<<16));
    }
}

__global__ __launch_bounds__(NT)
void decoder_kernel(const float* __restrict__ Xg,     // (1024,127,128)
                    const float* __restrict__ yprev,  // (1024,127)
                    const float* __restrict__ W1,     // (384,128)
                    const float* __restrict__ b1,
                    const float* __restrict__ W2,     // (128)
                    const float* __restrict__ b2v,
                    const float* __restrict__ Wfc,    // (129)
                    const float* __restrict__ bfcv,
                    const float* __restrict__ Wx,     // (512)
                    const float* __restrict__ blv,    // (512)
                    const float* __restrict__ Wf,     // (256)
                    const float* __restrict__ bfv,
                    const uint4* __restrict__ W1h,    // f16 octets [32][128]
                    const uint4* __restrict__ Whh,    // f16 octets [16][512]
                    float* __restrict__ out)          // (1024)
{
    // LDS total: 133120+4224+4224+8192+2048+2048+2048+2048+2048+512+32+64+2048 = 162,656
    __shared__ __align__(16) unsigned Eu [4*128*ROWW]; // E handoff -> Whh f16 cache
    __shared__ __align__(16) float  sdc  [4*SDCW];     // d/c f32, bank-split halves
    __shared__ __align__(16) float2 uws  [4*UWSW];     // (exp2(K2 u), -2*W2[e]), bank-split
    __shared__ __align__(16) float  zsc  [2048];       // [b*512+j] d@Wh; epilogue scratch
    __shared__ __align__(16) float  XWfcs[512];
    __shared__ __align__(16) float  betas[512];
    __shared__ __align__(16) float  ys   [512];
    __shared__ __align__(16) float4 wxf4 [128];
    __shared__ __align__(16) float4 blf4 [128];
    __shared__ float w2m2[128];
    __shared__ float params[8];                        // 0:wfcy 1:bfc 2:bf 4,5:pinit[h]
    __shared__ float swv[16];
    __shared__ __align__(16) __half sdch[1024];        // [b*256 + (d|c)] f16 mirror

    const int tid  = (int)threadIdx.x;
    const int lane = tid & 63;
    const int wave = tid >> 6;
    const int b0   = (int)blockIdx.x * 4;

    const uint4* sdch4 = (const uint4*)sdch;           // [b*32 + kq]: 8 f16 states, bcast
    __half* Eh = (__half*)Eu;

    // roles: u-waves = 0-3 (batches 0,1) and 12-15 (batches 2,3); z-waves = 4-11
    const bool is_u = (wave < 4) || (wave >= 12);
    const int  w4   = (wave < 4) ? wave : (wave - 12);
    const int  bsel = (wave < 4) ? 0 : 2;

    // phase-B mapping (t-invariant): lane -> (batch bB, row tpB, half hB)
    const int bB  = tid >> 8;
    const int tqB = (tid >> 6) & 3;
    const int tpB = tqB*32 + (lane >> 1);
    const int hB  = lane & 1;

    // ---- init ----
    if (tid < 128) {
        w2m2[tid] = -2.0f * W2[tid];
        wxf4[tid] = make_float4(Wx[tid],  Wx[128+tid],  Wx[256+tid],  Wx[384+tid]);
        blf4[tid] = make_float4(blv[tid], blv[128+tid], blv[256+tid], blv[384+tid]);
    }
    if (tid == 0) { params[0] = Wfc[NE]; params[1] = bfcv[0]; params[2] = bfv[0]; }
    if (tid == 4 || tid == 5) {                      // pinit[h] = b2/2 + sum W2[h-half]
        const int h = tid - 4;
        float s = b2v[0] * 0.5f;
        for (int i = 0; i < 64; ++i) s += W2[h*64 + i];
        params[4 + h] = s;
    }
    {   const int b = tid >> 8, r = tid & 255;       // d0 = c0 = X[b,0,0], bank-split f32
        sdc[b*SDCW + r + ((r >> 7) << 2)] = Xg[(size_t)(b0+b)*TM1*NE];
    }
    if (tid < 512) {                                 // f16 mirror of d0 and c0
        const int b = tid >> 7, g = tid & 127;
        const __half v = __float2half(Xg[(size_t)(b0+b)*TM1*NE]);
        sdch[b*256 + g] = v; sdch[b*256 + 128 + g] = v;
    }
    if (tid < 512) {
        const int b = tid >> 7, g = tid & 127;
        ys[tid] = (g < TM1) ? yprev[(size_t)(b0+b)*TM1 + g] : 0.0f;
        float xw = 0.0f;                             // XWfc[t'] = X[t'].Wfc[:128]
        if (g < TM1) {
            const float4* xr = (const float4*)(Xg + ((size_t)(b0+b)*TM1 + g)*NE);
            #pragma unroll 4
            for (int i = 0; i < 32; ++i) {
                const float4 x = xr[i];
                const float4 w = *(const float4*)&Wfc[i*4];
                xw = fmaf(x.x,w.x, fmaf(x.y,w.y, fmaf(x.z,w.z, fmaf(x.w,w.w, xw))));
            }
        }
        XWfcs[tid] = xw;                             // row 127 -> 0
    }
    if (tid < 260) {                                 // E row 127 = 0 (read into regs below)
        const int b = tid / 65, m = tid - b*65;
        Eu[(b*128 + 127)*ROWW + m] = 0u;
    }

    // ---- preamble: E = exp2(K2*(b1 + X@W1x)) as fp16 ----
    {
        const int eA = tid >> 3, oA = tid & 7;
        float w1x[16];
        #pragma unroll
        for (int m = 0; m < 16; ++m) w1x[m] = W1[(256 + oA*16 + m)*NE + eA];
        const float b1r = b1[eA];
        for (int b = 0; b < 4; ++b) {
            const float* Xbase = Xg + (size_t)(b0+b)*TM1*NE;
            for (int tp = 0; tp < TM1; ++tp) {
                const float4* xr = (const float4*)(Xbase + tp*NE + oA*16);
                float s0 = 0.f, s1 = 0.f;
                #pragma unroll
                for (int q = 0; q < 4; ++q) {
                    const float4 x = xr[q];
                    float& s = (q & 1) ? s1 : s0;
                    s = fmaf(w1x[q*4+0],x.x, fmaf(w1x[q*4+1],x.y,
                        fmaf(w1x[q*4+2],x.z, fmaf(w1x[q*4+3],x.w, s))));
                }
                float s = s0 + s1;
                s += __shfl_xor(s,1); s += __shfl_xor(s,2); s += __shfl_xor(s,4);
                if (oA == 0)
                    Eh[(b*128+tp)*2*ROWW + eA] = __float2half(EXP2(K2*(s + b1r)));
            }
        }
    }
    __syncthreads();

    // ---- E -> registers (t-invariant per lane) ----
    unsigned ereg[32];
    {
        const unsigned* Erow = Eu + (bB*128 + tpB)*ROWW + hB*32;
        #pragma unroll
        for (int i = 0; i < 32; ++i) ereg[i] = Erow[i];
    }
    __syncthreads();                                 // all reads of Eu done

    // ---- overlay Whh into dead Eu LDS (z LDS-fed; u streams W1h from L2) ----
    {
        const uint4* src = (const uint4*)Whh;        // 131072 B <= 133120 B (Eu)
        uint4* dst = (uint4*)Eu;
        #pragma unroll
        for (int i = 0; i < 8; ++i)
            dst[tid + i*1024] = src[tid + i*1024];
    }
    __syncthreads();
    const uint4* Whl4 = (const uint4*)Eu;            // f16 octets [16][512] in LDS

    for (int t = 0; t < TM1; ++t) {
        // ==== phase A: 8 u-waves (f16 dot2, W1h L2 stream); 8 z-waves (LDS dot2) ====
        if (is_u) {
            const int el = lane >> 1, kh = lane & 1;   // kh: d-half vs c-half of k
            const int e  = w4*32 + el;
            float a0=0.f, a1=0.f;
            #pragma unroll 4
            for (int k8 = 0; k8 < 16; ++k8) {
                const uint4 wq = W1h[(kh*16 + k8)*128 + e];        // L2 b128, shared addrs
                const uint4 dA = sdch4[(bsel  )*32 + kh*16 + k8];  // 2-addr LDS bcast
                const uint4 dB = sdch4[(bsel+1)*32 + kh*16 + k8];
                const h2* wh = (const h2*)&wq;
                const h2* eA = (const h2*)&dA;
                const h2* eB = (const h2*)&dB;
                #pragma unroll
                for (int p = 0; p < 4; ++p) {
                    a0 = DOT2(wh[p], eA[p], a0);
                    a1 = DOT2(wh[p], eB[p], a1);
                }
            }
            a0 += __shfl_xor(a0,1); a1 += __shfl_xor(a1,1);        // kh merge
            if (kh == 0) {
                const float w2 = w2m2[e];
                const int ei = e + ((e >> 6) << 1);                // bank-split index
                uws[ bsel   *UWSW + ei] = make_float2(EXP2(K2*a0), w2);
                uws[(bsel+1)*UWSW + ei] = make_float2(EXP2(K2*a1), w2);
            }
        } else {
            const int j = (wave - 4)*64 + lane;
            float a0=0.f, a1=0.f, a2=0.f, a3=0.f;
            #pragma unroll 4
            for (int k8 = 0; k8 < 16; ++k8) {
                const uint4 wq  = Whl4[k8*512 + j];          // b128, conflict-free
                const uint4 dq0 = sdch4[      k8];           // 8 f16 d's, uniform bcast
                const uint4 dq1 = sdch4[32 +  k8];
                const uint4 dq2 = sdch4[64 +  k8];
                const uint4 dq3 = sdch4[96 +  k8];
                const h2* wh = (const h2*)&wq;
                const h2* e0 = (const h2*)&dq0;  const h2* e1 = (const h2*)&dq1;
                const h2* e2 = (const h2*)&dq2;  const h2* e3 = (const h2*)&dq3;
                #pragma unroll
                for (int p = 0; p < 4; ++p) {
                    a0 = DOT2(wh[p], e0[p], a0);
                    a1 = DOT2(wh[p], e1[p], a1);
                    a2 = DOT2(wh[p], e2[p], a2);
                    a3 = DOT2(wh[p], e3[p], a3);
                }
            }
            zsc[       j] = a0; zsc[ 512 + j] = a1;
            zsc[1024 + j] = a2; zsc[1536 + j] = a3;
        }
        __syncthreads();                               // S1

        // ==== phase B: beta terms from E-regs: v=fma(E,EU,1); p=fma(w2,rcp(v),p) ====
        {
            const float4* uw4 = (const float4*)(uws + bB*UWSW + hB*66);
            float p0 = params[4 + hB], p1 = 0.f;
            #pragma unroll
            for (int i = 0; i < 32; ++i) {
                const unsigned ew = ereg[i];                 // registers, no LDS
                const float4 uw = uw4[i];                    // (EU0,w20,EU1,w21), 2 bcast
                const __half2 e2 = *(const __half2*)&ew;
                const float v0 = fmaf(__low2float (e2), uw.x, 1.0f);
                const float v1 = fmaf(__high2float(e2), uw.z, 1.0f);
                p0 = fmaf(uw.y, RCP(v0), p0);
                p1 = fmaf(uw.w, RCP(v1), p1);
            }
            float pb = p0 + p1;
            pb += __shfl_xor(pb, 1);                         // h-merge: full row sum
            if (t == TM1-1 && hB == 0 && tpB < TM1) betas[bB*128 + tpB] = pb;
            float prod = pb * XWfcs[bB*128 + tpB];           // row 127 -> *0
            prod += __shfl_xor(prod, 2);  prod += __shfl_xor(prod, 4);
            prod += __shfl_xor(prod, 8);  prod += __shfl_xor(prod, 16);
            prod += __shfl_xor(prod, 32);
            if (lane == 0) swv[wave] = prod;
        }
        __syncthreads();                               // S2

        // ==== gates (512 threads) ====
        if (tid < 512) {
            const int b = tid >> 7, g = tid & 127;
            const float ssum = (swv[b*4] + swv[b*4+1]) + (swv[b*4+2] + swv[b*4+3]);
            const float ytl  = fmaf(ys[b*128 + t], params[0], ssum + params[1]);
            const float4 wx = wxf4[g], bl = blf4[g];
            const float zi = fmaf(ytl, wx.x, bl.x) + zsc[b*512 +       g];
            const float zf = fmaf(ytl, wx.y, bl.y) + zsc[b*512 + 128 + g];
            const float zg = fmaf(ytl, wx.z, bl.z) + zsc[b*512 + 256 + g];
            const float zo = fmaf(ytl, wx.w, bl.w) + zsc[b*512 + 384 + g];
            const float c_old = sdc[b*SDCW + 132 + g];
            const float cn = fast_sig(zf)*c_old + fast_sig(zi)*fast_tanh(zg);
            const float dn = fast_sig(zo)*fast_tanh(cn);
            sdc[b*SDCW + g] = dn; sdc[b*SDCW + 132 + g] = cn;
            sdch[b*256 + g] = __float2half(dn);            // f16 mirrors for dot2
            sdch[b*256 + 128 + g] = __float2half(cn);
        }
        __syncthreads();                               // S3
    }

    // ---- epilogue: final ctx from betas + global X, then out ----
    if (tid < 512) {
        const int b = tid >> 7, e = tid & 127;
        const float* Xb = Xg + (size_t)(b0+b)*TM1*NE + e;
        float cacc = 0.0f;
        #pragma unroll 4
        for (int tp = 0; tp < TM1; ++tp)
            cacc = fmaf(betas[b*128 + tp], Xb[(size_t)tp*NE], cacc);
        zsc[tid] = fmaf(sdc[b*SDCW + e], Wf[e], cacc * Wf[128 + e]);
    }
    __syncthreads();
    if (tid < 4) {
        float s = 0.0f;
        for (int i = 0; i < 128; ++i) s += zsc[tid*128 + i];
        out[b0 + tid] = s + params[2];
    }
}

extern "C" void kernel_launch(void* const* d_in, const int* in_sizes, int n_in,
                              void* d_out, int out_size, void* d_ws, size_t ws_size,
                              hipStream_t stream) {
    (void)in_sizes; (void)n_in; (void)ws_size; (void)out_size;
    const float* Xg    = (const float*)d_in[0];
    const float* yprev = (const float*)d_in[1];
    const float* W1    = (const float*)d_in[2];
    const float* b1    = (const float*)d_in[3];
    const float* W2    = (const float*)d_in[4];
    const float* b2    = (const float*)d_in[5];
    const float* Wfc   = (const float*)d_in[6];
    const float* bfc   = (const float*)d_in[7];
    const float* Wx    = (const float*)d_in[8];
    const float* Wh    = (const float*)d_in[9];
    const float* bl    = (const float*)d_in[10];
    const float* Wf    = (const float*)d_in[11];
    const float* bf    = (const float*)d_in[12];

    uint4* W1h = (uint4*)d_ws;                         // 64 KB
    uint4* Whh = (uint4*)((char*)d_ws + 65536);        // 128 KB

    pack_weights<<<96, 256, 0, stream>>>(W1, Wh, W1h, Whh);
    decoder_kernel<<<NB, NT, 0, stream>>>(
        Xg, yprev, W1, b1, W2, b2, Wfc, bfc, Wx, bl, Wf, bf, W1h, Whh, (float*)d_out);
}